// Round 8
// baseline (60.856 us; speedup 1.0000x reference)
//
#include <hip/hip_runtime.h>
#include <hip/hip_fp16.h>
#include <math.h>

#define A 5
#define S 1024
#define T 1024
#define KCH 8
#define B0 128
#define L 8192
#define NPROB 1000
#define EPSF 1e-12f
#define NTHR 640               // 10 waves: 2 per ability

__device__ __forceinline__ float sigmoidf_(float x) {
    return 1.0f / (1.0f + __expf(-x));
}

struct ExSlot { float pf; __half2 p; };   // 8 B

// One block per STUDENT. Waves (2 per ability) iterate the student's 8
// chunks serially: filter chunk (wave-parallel 2x2 scan, CHUNK=8/lane),
// exchange (pf, p0, p1) via LDS, combine across abilities, write out.
// No cross-block communication at all.
__global__ __launch_bounds__(NTHR) void bkt_student_kernel(
    const float* __restrict__ dyn_logits,   // [50][3]
    const float* __restrict__ obs_kc,       // [50][2]
    const float* __restrict__ obs_prob,     // [1000][2]
    const float* __restrict__ abil,         // [5]
    const int*   __restrict__ trial,        // [S][T]
    const int*   __restrict__ problem,      // [S][T]
    const int*   __restrict__ correct,      // [S][T]
    const int*   __restrict__ kc,           // [S]
    float* __restrict__ out)                // [B0][L][2]
{
    __shared__ float2 s_e[NPROB];           // 8 KB exp table
    __shared__ ExSlot s_ex[A][1024];        // 40 KB exchange
    __shared__ float  s_m0[A][4];           // half0 chunk matrix
    __shared__ float  s_llw[A];             // half0 chunk ll total
    __shared__ float  s_tot[A];             // full chunk ll total
    __shared__ int    s_len[KCH];           // valid length per chunk

    int b = blockIdx.x;
    int w = threadIdx.x >> 6;               // wave 0..9
    int lane = threadIdx.x & 63;
    int a = w >> 1;                         // ability
    int half = w & 1;                       // which 512-slot half of the chunk

    for (int i = threadIdx.x; i < NPROB; i += NTHR) {
        float2 op = ((const float2*)obs_prob)[i];
        s_e[i] = make_float2(__expf(-op.x), __expf(op.y));
    }
    if (w < KCH) {                          // wave w -> length of chunk w
        const int* tr = trial + (size_t)(b * KCH + w) * T;
        int v1 = tr[896 + lane] != -1;
        int v2 = tr[960 + lane] != -1;
        unsigned long long m1 = __ballot(v1), m2 = __ballot(v2);
        if (lane == 0) s_len[w] = 896 + __popcll(m1) + __popcll(m2);
    }
    __syncthreads();

    float ability = abil[a];
    float base = 0.0f;                      // ll prefix base (per ability)
    int t0l = half * 512 + lane * 8;        // slot within chunk

    for (int k = 0; k < KCH; ++k) {
        int s = b * KCH + k;
        int kcs = kc[s];
        int len_s = s_len[k];
        float pL = sigmoidf_(dyn_logits[kcs * 3 + 0]);
        float pF = sigmoidf_(dyn_logits[kcs * 3 + 1]);
        float pI = sigmoidf_(dyn_logits[kcs * 3 + 2]);
        float ok0 = obs_kc[kcs * 2 + 0];
        float ok1 = obs_kc[kcs * 2 + 1];
        float t00 = 1.0f - pL, t01 = pF, t10 = pL, t11 = 1.0f - pF;
        float c0 = __expf(-ok0 - ability);  // pc0 = rcp(1 + e.x*c0)
        float c1 = __expf( ok1 - ability);  // pc1 = rcp(1 + e.y*c1)

        const int4* pv4 = (const int4*)(problem + (size_t)s * T + t0l);
        const int4* cv4 = (const int4*)(correct + (size_t)s * T + t0l);
        int4 pva = pv4[0], pvb = pv4[1];
        int4 cva = cv4[0], cvb = cv4[1];
        int pj[8] = {pva.x, pva.y, pva.z, pva.w, pvb.x, pvb.y, pvb.z, pvb.w};
        int cj[8] = {cva.x, cva.y, cva.z, cva.w, cvb.x, cvb.y, cvb.z, cvb.w};
        int cmask = 0, vmask = 0;
        #pragma unroll
        for (int j = 0; j < 8; ++j) {
            cmask |= (cj[j] & 1) << j;
            vmask |= ((t0l + j) < len_s) << j;
        }

        // ---- Phase 1: per-lane chunk matrix product ----
        float pc0a[8], pc1a[8];
        float p00 = 1.0f, p01 = 0.0f, p10 = 0.0f, p11 = 1.0f;
        #pragma unroll
        for (int j = 0; j < 8; ++j) {
            float2 e = s_e[pj[j]];
            float pc0 = __builtin_amdgcn_rcpf(1.0f + e.x * c0);
            float pc1 = __builtin_amdgcn_rcpf(1.0f + e.y * c1);
            pc0a[j] = pc0; pc1a[j] = pc1;
            bool c = (cmask >> j) & 1;
            float lik0 = c ? pc0 : 1.0f - pc0;
            float lik1 = c ? pc1 : 1.0f - pc1;
            float r0 = lik0 * p00, r1 = lik1 * p10;
            float r2 = lik0 * p01, r3 = lik1 * p11;
            p00 = t00 * r0 + t01 * r1;
            p10 = t10 * r0 + t11 * r1;
            p01 = t00 * r2 + t01 * r3;
            p11 = t10 * r2 + t11 * r3;
            if ((j & 3) == 3) {
                float inv = __builtin_amdgcn_rcpf(p00 + p01 + p10 + p11);
                p00 *= inv; p01 *= inv; p10 *= inv; p11 *= inv;
            }
        }

        // ---- Phase 2a: intra-wave inclusive matrix scan ----
        float q00 = p00, q01 = p01, q10 = p10, q11 = p11;
        #pragma unroll
        for (int off = 1; off < 64; off <<= 1) {
            float o00 = __shfl_up(q00, off);
            float o01 = __shfl_up(q01, off);
            float o10 = __shfl_up(q10, off);
            float o11 = __shfl_up(q11, off);
            if (lane >= off) {
                float n00 = q00 * o00 + q01 * o10;
                float n01 = q00 * o01 + q01 * o11;
                float n10 = q10 * o00 + q11 * o10;
                float n11 = q10 * o01 + q11 * o11;
                q00 = n00; q01 = n01; q10 = n10; q11 = n11;
            }
            if (off == 8 || off == 32) {
                float inv = __builtin_amdgcn_rcpf(fmaxf(q00 + q01 + q10 + q11, 1e-30f));
                q00 *= inv; q01 *= inv; q10 *= inv; q11 *= inv;
            }
        }
        if (half == 0 && lane == 63) {
            float inv = __builtin_amdgcn_rcpf(fmaxf(q00 + q01 + q10 + q11, 1e-30f));
            s_m0[a][0] = q00 * inv; s_m0[a][1] = q01 * inv;
            s_m0[a][2] = q10 * inv; s_m0[a][3] = q11 * inv;
        }
        __syncthreads();                    // B1: s_m0 ready

        // ---- Phase 2b: exclusive prefix; upper half composes wave0 total ----
        float e00 = __shfl_up(q00, 1), e01 = __shfl_up(q01, 1);
        float e10 = __shfl_up(q10, 1), e11 = __shfl_up(q11, 1);
        if (lane == 0) { e00 = 1.0f; e01 = 0.0f; e10 = 0.0f; e11 = 1.0f; }
        if (half == 1) {
            float m00 = s_m0[a][0], m01 = s_m0[a][1];
            float m10 = s_m0[a][2], m11 = s_m0[a][3];
            float n00 = e00 * m00 + e01 * m10;
            float n01 = e00 * m01 + e01 * m11;
            float n10 = e10 * m00 + e11 * m10;
            float n11 = e10 * m01 + e11 * m11;
            e00 = n00; e01 = n01; e10 = n10; e11 = n11;
        }
        float a0 = e00 * (1.0f - pI) + e01 * pI;
        float a1 = e10 * (1.0f - pI) + e11 * pI;
        {
            float inv = __builtin_amdgcn_rcpf(fmaxf(a0 + a1, EPSF));
            a0 *= inv; a1 *= inv;
        }

        // ---- Phase 3: replay with unnormalized alpha ----
        float ll[8];
        float llsum = 0.0f;
        #pragma unroll
        for (int j = 0; j < 8; ++j) {
            float pc0 = pc0a[j], pc1 = pc1a[j];
            bool c = (cmask >> j) & 1;
            bool valid = (vmask >> j) & 1;
            float num = a0 * pc0 + a1 * pc1;
            float den = a0 + a1;
            float pcor = num * __builtin_amdgcn_rcpf(den);
            float p0v = 1.0f - pcor;
            float py = c ? pcor : p0v;
            float llj = valid ? __logf(fmaxf(py, EPSF)) : 0.0f;
            ll[j] = llj; llsum += llj;
            pc0a[j] = valid ? p0v : 1.0f;
            pc1a[j] = valid ? pcor : 1.0f;
            float lik0 = c ? pc0 : 1.0f - pc0;
            float lik1 = c ? pc1 : 1.0f - pc1;
            float q0 = a0 * lik0, q1 = a1 * lik1;
            a0 = q0 * t00 + q1 * t01;
            a1 = q0 * t10 + q1 * t11;
            if ((j & 3) == 3) {
                float inv = __builtin_amdgcn_rcpf(fmaxf(a0 + a1, EPSF));
                a0 *= inv; a1 *= inv;
            }
        }

        // ---- obs-ll scan: intra-wave, then cross-half handoff ----
        float incl = llsum;
        #pragma unroll
        for (int off = 1; off < 64; off <<= 1) {
            float o = __shfl_up(incl, off);
            if (lane >= off) incl += o;
        }
        if (half == 0 && lane == 63) s_llw[a] = incl;
        __syncthreads();                    // B2: s_llw ready
        float excl = incl - llsum;
        if (half == 1) {
            float w0 = s_llw[a];
            excl += w0;
            float tot = w0 + __shfl(incl, 63);
            if (lane == 63) s_tot[a] = tot;
        }

        // ---- exchange write: pf (f32) + probs (half2) ----
        float run = base + excl;
        #pragma unroll
        for (int j = 0; j < 8; ++j) {
            ExSlot e;
            e.pf = run;
            e.p = __floats2half2_rn(pc0a[j], pc1a[j]);
            s_ex[a][t0l + j] = e;
            run += ll[j];
        }
        __syncthreads();                    // B3: exchange + s_tot ready

        // ---- combine across abilities; write out ----
        int t = threadIdx.x;
        if (t < 512) {
            float o[4];
            #pragma unroll
            for (int u = 0; u < 2; ++u) {
                int sl = 2 * t + u;
                float pf[A]; float2 pp[A];
                float pm = -INFINITY;
                #pragma unroll
                for (int aa = 0; aa < A; ++aa) {
                    ExSlot e = s_ex[aa][sl];
                    pf[aa] = e.pf;
                    pp[aa] = __half22float2(e.p);
                    pm = fmaxf(pm, e.pf);
                }
                float Se = 0.0f, S0 = 0.0f, S1 = 0.0f;
                #pragma unroll
                for (int aa = 0; aa < A; ++aa) {
                    float ee = __expf(pf[aa] - pm);
                    Se += ee;
                    S0 += ee * pp[aa].x;
                    S1 += ee * pp[aa].y;
                }
                float ls = __logf(Se);
                o[2*u]   = __logf(S0) - ls;
                o[2*u+1] = __logf(S1) - ls;
            }
            float* op = out + 2 * ((size_t)b * L + k * T + 2 * t);
            *(float4*)op = make_float4(o[0], o[1], o[2], o[3]);
        }
        base += s_tot[a];                   // read post-B3; next write post-B2'
    }
}

extern "C" void kernel_launch(void* const* d_in, const int* in_sizes, int n_in,
                              void* d_out, int out_size, void* d_ws, size_t ws_size,
                              hipStream_t stream) {
    const float* dyn  = (const float*)d_in[0];
    const float* okc  = (const float*)d_in[1];
    const float* oprb = (const float*)d_in[2];
    const float* ab   = (const float*)d_in[3];
    const int* trial  = (const int*)d_in[4];
    const int* prob   = (const int*)d_in[5];
    const int* corr   = (const int*)d_in[6];
    const int* kc     = (const int*)d_in[7];
    float* out = (float*)d_out;

    bkt_student_kernel<<<B0, NTHR, 0, stream>>>(
        dyn, okc, oprb, ab, trial, prob, corr, kc, out);
}